// Round 4
// baseline (588.828 us; speedup 1.0000x reference)
//
#include <hip/hip_runtime.h>

#define IN_F 8192
#define OUT_F 8192

typedef float v4f __attribute__((ext_vector_type(4)));

// Block-per-row (R1 structure) + max per-wave MLP:
// all 24 row loads (8 states, 8 trace, 8 x float4s) burst-issue into register
// arrays BEFORE any consumption -> 24 outstanding loads per wave.
// Phase 2 is load-free: compute from regs, nontemporal store.
// __launch_bounds__(256,4): 4 waves/SIMD -> 128-VGPR budget, fits ~112 live.
__global__ __launch_bounds__(256, 4) void snn_fused_kernel(
    const float* __restrict__ x,       // [IN_F]
    const float* __restrict__ states,  // [OUT_F, IN_F]
    const float* __restrict__ mp,      // [OUT_F]
    const float* __restrict__ thr,     // [OUT_F]
    const float* __restrict__ trace,   // [OUT_F, IN_F]
    float* __restrict__ out)           // spikes[O] | v[O] | thr[O] | trace[O*I]
{
    const int o = blockIdx.x;
    const int t = threadIdx.x;

    __shared__ float red_ws[4];
    __shared__ float red_dot[4];

    const v4f* __restrict__ x4  = (const v4f*)x;
    const v4f* __restrict__ s4  = (const v4f*)(states + (size_t)o * IN_F);
    const v4f* __restrict__ tr4 = (const v4f*)(trace  + (size_t)o * IN_F);

    // ---- burst-issue all 24 loads (no consumption in between) ----
    v4f sv[8], tr[8], xr[8];
#pragma unroll
    for (int k = 0; k < 8; ++k)
        sv[k] = __builtin_nontemporal_load(&s4[t + (k << 8)]);  // HBM stream, don't pollute L3
#pragma unroll
    for (int k = 0; k < 8; ++k)
        tr[k] = tr4[t + (k << 8)];                              // L3-hot: normal cached load
#pragma unroll
    for (int k = 0; k < 8; ++k)
        xr[k] = x4[t + (k << 8)];                               // L1/L2-hot

    const float mp_o  = mp[o];
    const float thr_o = thr[o];

    // ---- phase 1: dot + weight-count from regs ----
    float wsum = 0.0f, dot = 0.0f;
#pragma unroll
    for (int k = 0; k < 8; ++k) {
        const float w0 = (sv[k][0] > 50.0f) ? 1.0f : 0.0f;
        const float w1 = (sv[k][1] > 50.0f) ? 1.0f : 0.0f;
        const float w2 = (sv[k][2] > 50.0f) ? 1.0f : 0.0f;
        const float w3 = (sv[k][3] > 50.0f) ? 1.0f : 0.0f;
        wsum += (w0 + w1) + (w2 + w3);
        dot  += (w0 * xr[k][0] + w1 * xr[k][1]) + (w2 * xr[k][2] + w3 * xr[k][3]);
    }

    // 64-lane wave reduce, then 4-partial LDS reduce
#pragma unroll
    for (int off = 32; off > 0; off >>= 1) {
        wsum += __shfl_down(wsum, off);
        dot  += __shfl_down(dot,  off);
    }
    const int wave = t >> 6;
    if ((t & 63) == 0) { red_ws[wave] = wsum; red_dot[wave] = dot; }
    __syncthreads();

    // every thread computes spike redundantly (sums are exact integers in f32)
    const float ws = (red_ws[0] + red_ws[1]) + (red_ws[2] + red_ws[3]);
    const float dt = (red_dot[0] + red_dot[1]) + (red_dot[2] + red_dot[3]);
    const float conn  = fmaxf(ws, 5.0f);
    const float v     = mp_o * 0.85f + dt * (15.0f / sqrtf(conn));
    const float spike = (v >= thr_o) ? 1.0f : 0.0f;

    if (t == 0) {
        out[o]             = spike;
        out[OUT_F + o]     = v * (1.0f - spike) * 0.1f;
        out[2 * OUT_F + o] = fminf(fmaxf(thr_o + (spike - 0.1f) * 0.1f, 2.0f), 15.0f);
    }

    // ---- phase 2: load-free, compute from regs + nontemporal store ----
    v4f* __restrict__ ot4 = (v4f*)(out + 3 * OUT_F + (size_t)o * IN_F);
#pragma unroll
    for (int k = 0; k < 8; ++k) {
        v4f r;
        r[0] = fminf(fmaxf(tr[k][0] * 0.9f + spike * xr[k][0], 0.0f), 5.0f);
        r[1] = fminf(fmaxf(tr[k][1] * 0.9f + spike * xr[k][1], 0.0f), 5.0f);
        r[2] = fminf(fmaxf(tr[k][2] * 0.9f + spike * xr[k][2], 0.0f), 5.0f);
        r[3] = fminf(fmaxf(tr[k][3] * 0.9f + spike * xr[k][3], 0.0f), 5.0f);
        __builtin_nontemporal_store(r, &ot4[t + (k << 8)]);
    }
}

extern "C" void kernel_launch(void* const* d_in, const int* in_sizes, int n_in,
                              void* d_out, int out_size, void* d_ws, size_t ws_size,
                              hipStream_t stream) {
    const float* x      = (const float*)d_in[0];  // spike_input [8192]
    const float* states = (const float*)d_in[1];  // synapse_states [8192*8192]
    const float* mp     = (const float*)d_in[2];  // membrane_potential [8192]
    const float* thr    = (const float*)d_in[3];  // adaptive_threshold [8192]
    const float* trace  = (const float*)d_in[4];  // eligibility_trace [8192*8192]
    float* out = (float*)d_out;

    snn_fused_kernel<<<OUT_F, 256, 0, stream>>>(x, states, mp, thr, trace, out);
}

// Round 5
// 564.244 us; speedup vs baseline: 1.0436x; 1.0436x over previous
//
#include <hip/hip_runtime.h>

#define IN_F 8192
#define OUT_F 8192

typedef float v4f __attribute__((ext_vector_type(4)));

// ---------------- Kernel A: per-row reduce (read-only stream) ----------------
// Block-per-row, 256 threads. Streams the states row (nt), reduces
// wsum/dot, thread 0 writes spike / new_v / new_thr.
__global__ __launch_bounds__(256) void snn_reduce_kernel(
    const float* __restrict__ x,       // [IN_F]
    const float* __restrict__ states,  // [OUT_F, IN_F]
    const float* __restrict__ mp,      // [OUT_F]
    const float* __restrict__ thr,     // [OUT_F]
    float* __restrict__ out)           // spikes[O] | v[O] | thr[O] | ...
{
    const int o = blockIdx.x;
    const int t = threadIdx.x;

    __shared__ float red_ws[4];
    __shared__ float red_dot[4];

    const v4f* __restrict__ x4 = (const v4f*)x;
    const v4f* __restrict__ s4 = (const v4f*)(states + (size_t)o * IN_F);

    float wsum = 0.0f, dot = 0.0f;
#pragma unroll
    for (int k = 0; k < 8; ++k) {
        const int idx = t + (k << 8);
        const v4f sv = __builtin_nontemporal_load(&s4[idx]);  // single-use stream
        const v4f xv = x4[idx];                               // cache-resident
        const float w0 = (sv[0] > 50.0f) ? 1.0f : 0.0f;
        const float w1 = (sv[1] > 50.0f) ? 1.0f : 0.0f;
        const float w2 = (sv[2] > 50.0f) ? 1.0f : 0.0f;
        const float w3 = (sv[3] > 50.0f) ? 1.0f : 0.0f;
        wsum += (w0 + w1) + (w2 + w3);
        dot  += (w0 * xv[0] + w1 * xv[1]) + (w2 * xv[2] + w3 * xv[3]);
    }

#pragma unroll
    for (int off = 32; off > 0; off >>= 1) {
        wsum += __shfl_down(wsum, off);
        dot  += __shfl_down(dot,  off);
    }
    const int wave = t >> 6;
    if ((t & 63) == 0) { red_ws[wave] = wsum; red_dot[wave] = dot; }
    __syncthreads();

    if (t == 0) {
        const float ws = (red_ws[0] + red_ws[1]) + (red_ws[2] + red_ws[3]);
        const float dt = (red_dot[0] + red_dot[1]) + (red_dot[2] + red_dot[3]);
        const float conn  = fmaxf(ws, 5.0f);
        const float v     = mp[o] * 0.85f + dt * (15.0f / sqrtf(conn));
        const float th    = thr[o];
        const float spike = (v >= th) ? 1.0f : 0.0f;
        out[o]             = spike;
        out[OUT_F + o]     = v * (1.0f - spike) * 0.1f;
        out[2 * OUT_F + o] = fminf(fmaxf(th + (spike - 0.1f) * 0.1f, 2.0f), 15.0f);
    }
}

// ---------------- Kernel B: trace update (pure elementwise stream) -----------
// Each block covers half a row (1024 float4s); each thread 4 float4s.
// No barriers, no reduction -> fill-kernel-like streaming behavior.
__global__ __launch_bounds__(256) void snn_trace_kernel(
    const float* __restrict__ x,       // [IN_F]
    const float* __restrict__ trace,   // [OUT_F, IN_F]
    const float* __restrict__ spikes,  // out[0..OUT_F) written by kernel A
    float* __restrict__ out_trace)     // out + 3*OUT_F
{
    const int t    = threadIdx.x;
    const int row  = blockIdx.x >> 1;          // 2 blocks per row
    const int half = blockIdx.x & 1;           // which half-row

    const float spike = spikes[row];

    const v4f* __restrict__ x4  = (const v4f*)x;
    const v4f* __restrict__ tr4 = (const v4f*)(trace + (size_t)row * IN_F);
    v4f* __restrict__ ot4       = (v4f*)(out_trace + (size_t)row * IN_F);

    const int base = (half << 10) + t;         // half*1024 + t
#pragma unroll
    for (int k = 0; k < 4; ++k) {
        const int idx = base + (k << 8);
        const v4f tv = __builtin_nontemporal_load(&tr4[idx]);  // single-use
        const v4f xv = x4[idx];                                // cache-resident
        v4f r;
        r[0] = fminf(fmaxf(tv[0] * 0.9f + spike * xv[0], 0.0f), 5.0f);
        r[1] = fminf(fmaxf(tv[1] * 0.9f + spike * xv[1], 0.0f), 5.0f);
        r[2] = fminf(fmaxf(tv[2] * 0.9f + spike * xv[2], 0.0f), 5.0f);
        r[3] = fminf(fmaxf(tv[3] * 0.9f + spike * xv[3], 0.0f), 5.0f);
        __builtin_nontemporal_store(r, &ot4[idx]);
    }
}

extern "C" void kernel_launch(void* const* d_in, const int* in_sizes, int n_in,
                              void* d_out, int out_size, void* d_ws, size_t ws_size,
                              hipStream_t stream) {
    const float* x      = (const float*)d_in[0];  // spike_input [8192]
    const float* states = (const float*)d_in[1];  // synapse_states [8192*8192]
    const float* mp     = (const float*)d_in[2];  // membrane_potential [8192]
    const float* thr    = (const float*)d_in[3];  // adaptive_threshold [8192]
    const float* trace  = (const float*)d_in[4];  // eligibility_trace [8192*8192]
    float* out = (float*)d_out;

    snn_reduce_kernel<<<OUT_F, 256, 0, stream>>>(x, states, mp, thr, out);
    // same stream -> B sees A's spikes (kernel boundary flushes/acquires L2)
    snn_trace_kernel<<<OUT_F * 2, 256, 0, stream>>>(x, trace, out, out + 3 * OUT_F);
}